// Round 7
// baseline (213.933 us; speedup 1.0000x reference)
//
#include <hip/hip_runtime.h>

// Fused 2-layer LSTM (B=4096, T=512, I=H=32) + projection — PLAIN FP16 MFMA, 16 waves.
// Round-7: SKEW-2 symmetric layer pipeline. Iter i: L1 waves compute step i; L2 waves
// compute step i-2. Both roles' input-part GEMMs (L1: x(t), L2: h1(s)) are prefetched one
// iter ahead (off the critical path). Post-barrier critical work per wave = 1 ds_read +
// 1 dependent MFMA + activations + 1 LDS write. One barrier per iter; 2 epilogue iters.
//
// Decomposition (v6, proven finest): 256 WGs x 1024 thr = 16 waves (4/SIMD). Waves 0-7:
// L1 M-tile t=wv (units t*4..t*4+3); waves 8-15: L2 tile t=wv-8. Lane owns ONE cell
// (unit t*4+(l>>4), batch l&15): D regs = (i,f,g,o) -> lane-local update, 10 trans/step.
// Weights fp16 in registers, pre-scaled by -log2e (i,f,o) / -2log2e (g):
// sigmoid = rcp(1+exp2(acc)). fp32 accumulate. Measured error below harness floor.
//
// Buffers: H1 slot i&1 = h1(i); L1 reads H1[(i-1)&1]; L2's pE prefetch reads H1[(i-1)&1]
// at iter i (stable; that slot is rewritten only at iter i+1, after a barrier). H2 slot
// s&1 = h2(s), s = i-2; L2 reads H2[(s-1)&1] post-barrier. All hazards barrier-separated.
// Epilogue iters 512/513: L2 computes steps 510/511; h2(511) lands in fp32 HF.

typedef __attribute__((ext_vector_type(4))) float f32x4;
typedef _Float16 half8 __attribute__((ext_vector_type(8)));

#define MFMA_F16(a, b, c) __builtin_amdgcn_mfma_f32_16x16x32_f16(a, b, c, 0, 0, 0)

namespace {
constexpr int TSTEPS = 512;
constexpr int CT     = 16;
constexpr float LOG2E = 1.4426950408889634f;

// acc = -log2e * z  ->  sigmoid(z) = rcp(1 + exp2(acc))
__device__ __forceinline__ float sigm2(float a) {
    return __builtin_amdgcn_rcpf(1.0f + __builtin_amdgcn_exp2f(a));
}

// acc = (i,f,g,o) pre-scaled preacts of one cell; updates c, returns h.
__device__ __forceinline__ float act_gate(const f32x4 acc, float& c) {
    const float iv = sigm2(acc[0]);
    const float fv = sigm2(acc[1]);
    const float gv = fmaf(2.0f, sigm2(acc[2]), -1.0f);   // tanh(z) = 2*sigma(2z)-1
    const float ov = sigm2(acc[3]);
    const float cc = fmaf(fv, c, iv * gv);
    c = cc;
    return ov * fmaf(2.0f, sigm2(cc * (-2.0f * LOG2E)), -1.0f);
}
}  // namespace

__global__ __launch_bounds__(1024, 1)
void lstm2_v7(const float* __restrict__ x,
              const float* __restrict__ Wih1, const float* __restrict__ Whh1,
              const float* __restrict__ bih1, const float* __restrict__ bhh1,
              const float* __restrict__ Wih2, const float* __restrict__ Whh2,
              const float* __restrict__ bih2, const float* __restrict__ bhh2,
              const float* __restrict__ Wproj, const float* __restrict__ bproj,
              float* __restrict__ out)
{
    // frag-unit layout: frag index = slab*64 + kg*16 + (col ^ (kg<<1)); 16B per frag
    __shared__ half8 XA[CT * 4 * 16];   // 16 KB: x chunk   (slab = tt)
    __shared__ half8 H1[2 * 4 * 16];    // 2 KB             (slab = parity)
    __shared__ half8 H2[2 * 4 * 16];    // 2 KB
    __shared__ float HF[16 * 33];
    __shared__ float WPs[16 * 33];
    __shared__ float BPs[16];

    const int tid  = threadIdx.x;
    const int wv   = tid >> 6;        // 0..15
    const int Lly  = wv >> 3;         // 0: L1 waves, 1: L2 waves
    const int t    = wv & 7;          // M-tile (units t*4..t*4+3)
    const int l    = tid & 63;
    const int colB = l & 15;          // batch (B col / A row / D col)
    const int g    = l >> 4;          // k-group; D row group -> lane's unit = t*4+g

    // ---- persistent fp16 register weights (A-frags), unit-major reorder, pre-scaled ----
    half8 Wi, Wr;
    f32x4 bias;
    {
        const float* WI = Lly ? Wih2 : Wih1;
        const float* WH = Lly ? Whh2 : Whh1;
        const float* BI = Lly ? bih2 : bih1;
        const float* BH = Lly ? bhh2 : bhh1;
        const int q = colB & 3;
        const int R = q * 32 + t * 4 + (colB >> 2);
        const float sw = ((q == 2) ? -2.0f : -1.0f) * LOG2E;
#pragma unroll
        for (int e = 0; e < 8; ++e) {
            Wi[e] = (_Float16)(WI[R * 32 + g * 8 + e] * sw);
            Wr[e] = (_Float16)(WH[R * 32 + g * 8 + e] * sw);
        }
#pragma unroll
        for (int qq = 0; qq < 4; ++qq) {
            const int Rb = qq * 32 + t * 4 + g;
            bias[qq] = (((qq == 2) ? -2.0f : -1.0f) * LOG2E) * (BI[Rb] + BH[Rb]);
        }
    }

    for (int i = tid; i < 16 * 32; i += 1024) WPs[(i >> 5) * 33 + (i & 31)] = Wproj[i];
    if (tid < 16) BPs[tid] = bproj[tid];
    {   // zero h state
        ushort* z1 = (ushort*)H1;
        ushort* z2 = (ushort*)H2;
        for (int i = tid; i < 2 * 4 * 16 * 8; i += 1024) { z1[i] = 0; z2[i] = 0; }
    }

    const size_t bglob = (size_t)blockIdx.x * 16;

    // lane's read-frag base (kg = g) and h-write scalar index
    const int fbase = g * 16 + (colB ^ (g << 1));          // + slab*64
    const int kgw   = t >> 1;
    const int hbw   = (kgw * 16 + (colB ^ (kgw << 1))) * 8 + (t & 1) * 4 + g;  // + par*512
    const int unit  = t * 4 + g;

    // x staging: thread -> (step st, batch sb, k-group kg); 32B global load, 16B LDS write
    const int kg = tid & 3;
    const int sb = (tid >> 2) & 15;
    const int st = tid >> 6;   // 0..15
    const float* xsrc = x + ((bglob + sb) * TSTEPS + st) * 32 + kg * 8;
    const int xslot = st * 64 + kg * 16 + (sb ^ (kg << 1));

    float4 xv0 = ((const float4*)xsrc)[0], xv1 = ((const float4*)xsrc)[1];

    float c = 0.f;     // lane's cell state (L1 or L2 per wave role)
    f32x4 pX;          // L1: bias + x-part for current step | L2: bias + h1-part (pE)
    pX = bias;         // L2 iter-0 garbage-safe init (commit guarded until i>=2)

    for (int t0 = 0; t0 < TSTEPS; t0 += CT) {
        // ---- write prefetched x chunk (fp16), prefetch next ----
        {
            half8 hv;
#pragma unroll
            for (int e = 0; e < 4; ++e) { hv[e] = (_Float16)xv0[e]; hv[4 + e] = (_Float16)xv1[e]; }
            XA[xslot] = hv;
        }
        if (t0 + CT < TSTEPS) {
            const float4* p = (const float4*)(xsrc + (size_t)(t0 + CT) * 32);
            xv0 = p[0]; xv1 = p[1];
        }
        __syncthreads();   // XA ready (also orders vs. prior chunk's reads)

        if (Lly == 0) {    // pX for tt=0 of this chunk
            pX = bias;
            pX = MFMA_F16(Wi, XA[0 * 64 + fbase], pX);
        }

#pragma unroll 2
        for (int tt = 0; tt < CT; ++tt) {
            const int i = t0 + tt, par = i & 1, parn = par ^ 1;

            if (Lly == 0) {
                // ---- L1 step i: post-barrier = 1 read + 1 MFMA + act + write ----
                const half8 hf = H1[parn * 64 + fbase];          // h1(i-1)
                f32x4 a = pX;
                a = MFMA_F16(Wr, hf, a);
                if (tt < CT - 1) {            // prefetch pX for step i+1 (XA only)
                    pX = bias;
                    pX = MFMA_F16(Wi, XA[(tt + 1) * 64 + fbase], pX);
                }
                const float h = act_gate(a, c);
                ((_Float16*)H1)[par * 512 + hbw] = (_Float16)h;
            } else {
                // ---- L2 step s = i-2: post-barrier = 1 read + 1 MFMA + act + write ----
                const half8 Hf  = H2[parn * 64 + fbase];         // h2(s-1): (s-1)&1 = parn
                const half8 hf1 = H1[parn * 64 + fbase];         // h1(i-1) for pE(s+1)
                if (i >= 2) {
                    f32x4 a = pX;                                // pE(s), prefetched
                    a = MFMA_F16(Wr, Hf, a);
                    const float h = act_gate(a, c);
                    ((_Float16*)H2)[par * 512 + hbw] = (_Float16)h;   // s&1 = par
                }
                pX = bias;                                       // pE(s+1) from h1(i-1)
                pX = MFMA_F16(Wi, hf1, pX);
            }
            __syncthreads();   // the ONE barrier per iter
        }
    }

    // ---- epilogue iter 512 (L2 step 510) ----
    if (Lly == 1) {
        const half8 Hf  = H2[1 * 64 + fbase];    // h2(509): (510-1)&1 = 1
        f32x4 a = pX;                             // pE(510) (prefetched at iter 511)
        a = MFMA_F16(Wr, Hf, a);
        const half8 hf1 = H1[1 * 64 + fbase];    // h1(511): 511&1 = 1
        const float h = act_gate(a, c);
        ((_Float16*)H2)[0 * 512 + hbw] = (_Float16)h;   // 510&1 = 0
        pX = bias;
        pX = MFMA_F16(Wi, hf1, pX);               // pE(511)
    }
    __syncthreads();
    // ---- epilogue iter 513 (L2 step 511) -> fp32 HF ----
    if (Lly == 1) {
        const half8 Hf = H2[0 * 64 + fbase];     // h2(510)
        f32x4 a = pX;
        a = MFMA_F16(Wr, Hf, a);
        HF[colB * 33 + unit] = act_gate(a, c);
    }
    __syncthreads();

    // ---- projection: out[b][m] ----
    if (tid < 256) {
        const int b = tid >> 4, m = tid & 15;
        float a = BPs[m];
        const float* hp = &HF[b * 33];
        const float* wp = &WPs[m * 33];
#pragma unroll
        for (int k = 0; k < 32; ++k) a = fmaf(hp[k], wp[k], a);
        out[(bglob + b) * 16 + m] = a;
    }
}

extern "C" void kernel_launch(void* const* d_in, const int* in_sizes, int n_in,
                              void* d_out, int out_size, void* d_ws, size_t ws_size,
                              hipStream_t stream) {
    const float* x     = (const float*)d_in[0];
    const float* Wih1  = (const float*)d_in[1];
    const float* Whh1  = (const float*)d_in[2];
    const float* bih1  = (const float*)d_in[3];
    const float* bhh1  = (const float*)d_in[4];
    const float* Wih2  = (const float*)d_in[5];
    const float* Whh2  = (const float*)d_in[6];
    const float* bih2  = (const float*)d_in[7];
    const float* bhh2  = (const float*)d_in[8];
    const float* Wproj = (const float*)d_in[9];
    const float* bproj = (const float*)d_in[10];
    float* out = (float*)d_out;

    dim3 grid(256), block(1024);
    lstm2_v7<<<grid, block, 0, stream>>>(x, Wih1, Whh1, bih1, bhh1,
                                         Wih2, Whh2, bih2, bhh2,
                                         Wproj, bproj, out);
}

// Round 8
// 191.940 us; speedup vs baseline: 1.1146x; 1.1146x over previous
//
#include <hip/hip_runtime.h>

// Fused 2-layer LSTM (B=4096, T=512, I=H=32) + projection — PLAIN FP16 MFMA, 16 waves.
// Round-8: v6 structure (proven best: 1 cell/lane, 16 waves, 4/SIMD, skew-1 pipeline)
// with FUSED activations: i*g and o*tanh(c) each computed with ONE combined rcp:
//   i*g      = (1-y) / ((1+xi)(1+y)),  xi=2^zi^, y=2^yg^ (g pre-scaled by -2log2e)
//   o*tanh(c)= (1-u) / ((1+xo)(1+u)),  u=2^(-2log2e*c)
// -> 5 exp2 + 3 rcp = 8 trans/cell (was 10). Algebraically identical to v6 (1-ulp diffs).
//
// Structure: grid 256 x 1024 thr = 16 waves (4/SIMD). Waves 0-7: L1 M-tile t=wv (units
// t*4..t*4+3); waves 8-15: L2 tile t=wv-8. Layer-pipelined: iter i computes L1 step i and
// L2 step i-1; 1 barrier/iter. Lane owns ONE cell (unit t*4+(l>>4), batch l&15): D regs =
// (i,f,g,o) -> lane-local update. L1: pX = bias + MFMA(Wi, x(t)) prefetched a step ahead.
// L2: e = bias+MFMA(Wi,h1), f = MFMA(Wr,h2) parallel, merged by v_add (v6 form — v7's
// pE prefetch regressed).
// Weights fp16 in registers, pre-scaled by -log2e (i,f,o) / -2log2e (g); fp32 accumulate.
//
// Buffers: H1 slot i&1 = h1(i); L1 reads H1[(i-1)&1]; L2 reads H1[(i-1)&1] and H2 slot
// (i-2)&1, writes H2[(i-1)&1]. All cross-iter hazards separated by the end-of-iter
// barrier. i=0: L2 commit guarded. Epilogue: L2 computes step 511 from H1[1], H2[0].

typedef __attribute__((ext_vector_type(4))) float f32x4;
typedef _Float16 half8 __attribute__((ext_vector_type(8)));

#define MFMA_F16(a, b, c) __builtin_amdgcn_mfma_f32_16x16x32_f16(a, b, c, 0, 0, 0)

namespace {
constexpr int TSTEPS = 512;
constexpr int CT     = 16;
constexpr float LOG2E = 1.4426950408889634f;

// acc = (zi^, zf^, yg^, zo^): pre-scaled preacts (-log2e*z for i,f,o; -2log2e*z for g).
// Fused-rcp gate evaluation; updates c, returns h. 5 exp2 + 3 rcp.
__device__ __forceinline__ float act_fused(const f32x4 acc, float& c) {
    const float xi = __builtin_amdgcn_exp2f(acc[0]);
    const float xf = __builtin_amdgcn_exp2f(acc[1]);
    const float y  = __builtin_amdgcn_exp2f(acc[2]);
    const float xo = __builtin_amdgcn_exp2f(acc[3]);
    const float fv = __builtin_amdgcn_rcpf(1.0f + xf);                       // sigma(zf)
    const float ig = (1.0f - y) * __builtin_amdgcn_rcpf((1.0f + xi) * (1.0f + y));
    const float cc = fmaf(fv, c, ig);
    c = cc;
    const float u  = __builtin_amdgcn_exp2f(cc * (-2.0f * LOG2E));
    return (1.0f - u) * __builtin_amdgcn_rcpf((1.0f + xo) * (1.0f + u));    // o*tanh(c)
}
}  // namespace

__global__ __launch_bounds__(1024, 1)
void lstm2_v8(const float* __restrict__ x,
              const float* __restrict__ Wih1, const float* __restrict__ Whh1,
              const float* __restrict__ bih1, const float* __restrict__ bhh1,
              const float* __restrict__ Wih2, const float* __restrict__ Whh2,
              const float* __restrict__ bih2, const float* __restrict__ bhh2,
              const float* __restrict__ Wproj, const float* __restrict__ bproj,
              float* __restrict__ out)
{
    // frag-unit layout: frag index = slab*64 + kg*16 + (col ^ (kg<<1)); 16B per frag
    __shared__ half8 XA[CT * 4 * 16];   // 16 KB: x chunk   (slab = tt)
    __shared__ half8 H1[2 * 4 * 16];    // 2 KB             (slab = parity)
    __shared__ half8 H2[2 * 4 * 16];    // 2 KB
    __shared__ float HF[16 * 33];
    __shared__ float WPs[16 * 33];
    __shared__ float BPs[16];

    const int tid  = threadIdx.x;
    const int wv   = tid >> 6;        // 0..15
    const int Lly  = wv >> 3;         // 0: L1 waves, 1: L2 waves
    const int t    = wv & 7;          // M-tile (units t*4..t*4+3)
    const int l    = tid & 63;
    const int colB = l & 15;          // batch (B col / A row / D col)
    const int g    = l >> 4;          // k-group; D row group -> lane's unit = t*4+g

    // ---- persistent fp16 register weights (A-frags), unit-major reorder, pre-scaled ----
    half8 Wi, Wr;
    f32x4 bias;
    {
        const float* WI = Lly ? Wih2 : Wih1;
        const float* WH = Lly ? Whh2 : Whh1;
        const float* BI = Lly ? bih2 : bih1;
        const float* BH = Lly ? bhh2 : bhh1;
        const int q = colB & 3;
        const int R = q * 32 + t * 4 + (colB >> 2);
        const float sw = ((q == 2) ? -2.0f : -1.0f) * LOG2E;
#pragma unroll
        for (int e = 0; e < 8; ++e) {
            Wi[e] = (_Float16)(WI[R * 32 + g * 8 + e] * sw);
            Wr[e] = (_Float16)(WH[R * 32 + g * 8 + e] * sw);
        }
#pragma unroll
        for (int qq = 0; qq < 4; ++qq) {
            const int Rb = qq * 32 + t * 4 + g;
            bias[qq] = (((qq == 2) ? -2.0f : -1.0f) * LOG2E) * (BI[Rb] + BH[Rb]);
        }
    }

    for (int i = tid; i < 16 * 32; i += 1024) WPs[(i >> 5) * 33 + (i & 31)] = Wproj[i];
    if (tid < 16) BPs[tid] = bproj[tid];
    {   // zero h state
        ushort* z1 = (ushort*)H1;
        ushort* z2 = (ushort*)H2;
        for (int i = tid; i < 2 * 4 * 16 * 8; i += 1024) { z1[i] = 0; z2[i] = 0; }
    }

    const size_t bglob = (size_t)blockIdx.x * 16;

    // lane's read-frag base (kg = g) and h-write scalar index
    const int fbase = g * 16 + (colB ^ (g << 1));          // + slab*64
    const int kgw   = t >> 1;
    const int hbw   = (kgw * 16 + (colB ^ (kgw << 1))) * 8 + (t & 1) * 4 + g;  // + par*512
    const int unit  = t * 4 + g;

    // x staging: thread -> (step st, batch sb, k-group kg); 32B global load, 16B LDS write
    const int kg = tid & 3;
    const int sb = (tid >> 2) & 15;
    const int st = tid >> 6;   // 0..15
    const float* xsrc = x + ((bglob + sb) * TSTEPS + st) * 32 + kg * 8;
    const int xslot = st * 64 + kg * 16 + (sb ^ (kg << 1));

    float4 xv0 = ((const float4*)xsrc)[0], xv1 = ((const float4*)xsrc)[1];

    float c = 0.f;     // lane's cell state (L1 or L2 per wave role)
    f32x4 pX;          // L1: precomputed bias + x-part for current step

    for (int t0 = 0; t0 < TSTEPS; t0 += CT) {
        // ---- write prefetched x chunk (fp16), prefetch next ----
        {
            half8 hv;
#pragma unroll
            for (int e = 0; e < 4; ++e) { hv[e] = (_Float16)xv0[e]; hv[4 + e] = (_Float16)xv1[e]; }
            XA[xslot] = hv;
        }
        if (t0 + CT < TSTEPS) {
            const float4* p = (const float4*)(xsrc + (size_t)(t0 + CT) * 32);
            xv0 = p[0]; xv1 = p[1];
        }
        __syncthreads();   // XA ready (also orders vs. prior chunk's reads)

        if (Lly == 0) {    // pX for tt=0 of this chunk
            pX = bias;
            pX = MFMA_F16(Wi, XA[0 * 64 + fbase], pX);
        }

#pragma unroll 2
        for (int tt = 0; tt < CT; ++tt) {
            const int i = t0 + tt, par = i & 1, parn = par ^ 1;

            if (Lly == 0) {
                // ---- L1 step i: chain = 1 MFMA after the h1 read ----
                const half8 hf = H1[parn * 64 + fbase];
                f32x4 a = pX;
                a = MFMA_F16(Wr, hf, a);
                if (tt < CT - 1) {            // precompute pX for step tt+1 (XA only)
                    pX = bias;
                    pX = MFMA_F16(Wi, XA[(tt + 1) * 64 + fbase], pX);
                }
                const float h = act_fused(a, c);
                ((_Float16*)H1)[par * 512 + hbw] = (_Float16)h;
            } else {
                // ---- L2 step i-1: two parallel 1-chains, merged ----
                const half8 hf = H1[parn * 64 + fbase];
                const half8 Hf = H2[par * 64 + fbase];
                f32x4 e_ = bias;
                f32x4 f_ = {0.f, 0.f, 0.f, 0.f};
                e_ = MFMA_F16(Wi, hf, e_);
                f_ = MFMA_F16(Wr, Hf, f_);
                if (i > 0) {
                    const float h = act_fused(e_ + f_, c);
                    ((_Float16*)H2)[parn * 512 + hbw] = (_Float16)h;
                }
            }
            __syncthreads();   // the ONE barrier per step
        }
    }

    // ---- epilogue: L2 step 511 from H1[1] (h1(511)) and H2[0] (h2(510)) ----
    if (Lly == 1) {
        const half8 hf = H1[1 * 64 + fbase];
        const half8 Hf = H2[0 * 64 + fbase];
        f32x4 e_ = bias;
        f32x4 f_ = {0.f, 0.f, 0.f, 0.f};
        e_ = MFMA_F16(Wi, hf, e_);
        f_ = MFMA_F16(Wr, Hf, f_);
        HF[colB * 33 + unit] = act_fused(e_ + f_, c);
    }
    __syncthreads();

    // ---- projection: out[b][m] ----
    if (tid < 256) {
        const int b = tid >> 4, m = tid & 15;
        float a = BPs[m];
        const float* hp = &HF[b * 33];
        const float* wp = &WPs[m * 33];
#pragma unroll
        for (int k = 0; k < 32; ++k) a = fmaf(hp[k], wp[k], a);
        out[(bglob + b) * 16 + m] = a;
    }
}

extern "C" void kernel_launch(void* const* d_in, const int* in_sizes, int n_in,
                              void* d_out, int out_size, void* d_ws, size_t ws_size,
                              hipStream_t stream) {
    const float* x     = (const float*)d_in[0];
    const float* Wih1  = (const float*)d_in[1];
    const float* Whh1  = (const float*)d_in[2];
    const float* bih1  = (const float*)d_in[3];
    const float* bhh1  = (const float*)d_in[4];
    const float* Wih2  = (const float*)d_in[5];
    const float* Whh2  = (const float*)d_in[6];
    const float* bih2  = (const float*)d_in[7];
    const float* bhh2  = (const float*)d_in[8];
    const float* Wproj = (const float*)d_in[9];
    const float* bproj = (const float*)d_in[10];
    float* out = (float*)d_out;

    dim3 grid(256), block(1024);
    lstm2_v8<<<grid, block, 0, stream>>>(x, Wih1, Whh1, bih1, bhh1,
                                         Wih2, Whh2, bih2, bhh2,
                                         Wproj, bproj, out);
}